// Round 23
// baseline (437.519 us; speedup 1.0000x reference)
//
#include <hip/hip_runtime.h>
#include <hip/hip_fp16.h>
#include <stdint.h>

// SymmetricQuantLinear: out[m,n] = scale[n] * sum_k x[m,k] * (nib(k,n) - 8)
// Round 23: R22 keeper with FULL-TILE staging lead: all 8 units of tile
//   k+1 issued at tile k entry; entry WAITV(0) drains units issued one
//   full tile (~2500cy) ago -> free; ONE barrier per tile, no mid-tile
//   sync; all 24 frag ds_reads hoistable under MFMA shadow (no barrier
//   between them). Single-variable vs R22 (sync structure only).
//   R21's full-lead failure was thin-tile (600cy < DMA); here 2500cy >> 900.

#define M_DIM 4096
#define K_DIM 4096
#define N_DIM 11008
#define KH    (K_DIM / 2)

#define WS_XH_BYTES  ((size_t)M_DIM * K_DIM * 2)            // 32 MiB

typedef __attribute__((ext_vector_type(8))) _Float16 f16x8;
typedef __attribute__((ext_vector_type(2))) _Float16 h2;
typedef __attribute__((ext_vector_type(4))) float f32x4;

__device__ __forceinline__ unsigned pack_f16_pair(float lo, float hi) {
    return __builtin_bit_cast(unsigned, __builtin_amdgcn_cvt_pkrtz(lo, hi));
}

__device__ __forceinline__ unsigned dq_pair(unsigned v) {
    unsigned c = (v & 0xFu) | ((v << 12) & 0x000F0000u) | 0x64006400u;
    h2 r = __builtin_bit_cast(h2, c) + __builtin_bit_cast(h2, 0xE408E408u);
    return __builtin_bit_cast(unsigned, r);
}

__device__ __forceinline__ void gld_lds16(const void* g, void* l) {
    __builtin_amdgcn_global_load_lds(
        (const __attribute__((address_space(1))) unsigned int*)g,
        (__attribute__((address_space(3))) unsigned int*)l,
        16, 0, 0);
}

// ---- Pass 1a: X f32 -> fp16 (exact) ----
__global__ void __launch_bounds__(256) cvt_x_kernel(
    const float* __restrict__ X, unsigned short* __restrict__ Xh)
{
    size_t i = ((size_t)blockIdx.x * 256 + threadIdx.x) * 8;
    float4 a = *(const float4*)(X + i);
    float4 b = *(const float4*)(X + i + 4);
    uint4 o = make_uint4(pack_f16_pair(a.x, a.y), pack_f16_pair(a.z, a.w),
                         pack_f16_pair(b.x, b.y), pack_f16_pair(b.z, b.w));
    *(uint4*)(Xh + i) = o;
}

// ---- Pass 1b: WP [KH][N] -> Wt uint32 [N][KH] ----
__global__ void __launch_bounds__(256) dqt_kernel(
    const int* __restrict__ WP, unsigned* __restrict__ Wt)
{
    __shared__ unsigned Lt[64][65];
    const int t = threadIdx.x;
    const int n0 = blockIdx.x * 64;
    const int r0 = blockIdx.y * 64;
    const int g = t >> 6, l = t & 63;
#pragma unroll
    for (int i = 0; i < 16; ++i) {
        const int r = r0 + g * 16 + i;
        Lt[l][g * 16 + i] = dq_pair((unsigned)WP[(size_t)r * N_DIM + n0 + l]);
    }
    __syncthreads();
    const int nr = t >> 2, sg = t & 3;
    unsigned* dst = Wt + (size_t)(n0 + nr) * KH + r0 + sg * 16;
#pragma unroll
    for (int c = 0; c < 4; ++c) {
        uint4 v = make_uint4(Lt[nr][sg * 16 + c * 4 + 0], Lt[nr][sg * 16 + c * 4 + 1],
                             Lt[nr][sg * 16 + c * 4 + 2], Lt[nr][sg * 16 + c * 4 + 3]);
        *(uint4*)(dst + c * 4) = v;
    }
}

// ---- Pass 2: full-tile-lead fp16 GEMM, 1 barrier/tile ----
__global__ void __launch_bounds__(512, 2) qgemm15_kernel(
    const unsigned short* __restrict__ Xh,   // fp16 [M][K]
    const unsigned*       __restrict__ Wt,   // uint32 [N][KH] (fp16 [N][K])
    const float*          __restrict__ WS,   // [N]
    float*                __restrict__ Out)  // f32 [M][N]
{
    __shared__ unsigned short LA[2][2][8192];   // [dbuf][half][128 x 64]
    __shared__ unsigned short LB[2][2][8192];   // 128 KB total

    const int t = threadIdx.x;     // 0..511
    const int w = t >> 6;          // wave 0..7
    const int l = t & 63;

    // XCD pairing: xcd owns M-rows {2x,2x+1}, N-major (R14: FETCH 403 MB).
    const int bid = blockIdx.x;                 // 0..687
    const int xcd = bid & 7;
    const int i8  = bid >> 3;                   // 0..85
    const int bx  = i8 >> 1;                    // 0..42
    const int by  = (xcd << 1) | (i8 & 1);      // 0..15
    const int bm0 = by * 256;
    const int bn0 = bx * 256;

    const int wr = w >> 2;         // A half
    const int wc = w & 3;          // B: half = wc>>1, sub = wc&1

    f32x4 acc[8][4];
#pragma unroll
    for (int i = 0; i < 8; ++i)
#pragma unroll
        for (int j = 0; j < 4; ++j)
            acc[i][j] = (f32x4){0.f, 0.f, 0.f, 0.f};

    // staging: unit = 64 rows x 64 ushort = 8 KB = 512 threads x 16 B.
    const int cS = (t & 7) ^ ((t >> 3) & 7);
    const unsigned short* gA = Xh + (size_t)(bm0 + (t >> 3)) * K_DIM + cS * 8;
    const unsigned*       gB = Wt + (size_t)(bn0 + (t >> 3)) * KH + cS * 4;
    const int t8 = t * 8;

#define SU_A(buf, h, c, kt)                                                   \
    gld_lds16(gA + (size_t)((h) * 128 + (c) * 64) * K_DIM + (size_t)(kt) * 64, \
              &LA[buf][h][(c) * 4096 + t8])
#define SU_B(buf, bh, ch, kt)                                                 \
    gld_lds16(gB + (size_t)((bh) * 128 + (ch) * 64) * KH + (size_t)(kt) * 32, \
              &LB[buf][bh][(ch) * 4096 + t8])

#define STAGE8(buf, kt) do {                                                  \
    SU_B(buf, 0, 0, kt); SU_B(buf, 0, 1, kt);                                 \
    SU_B(buf, 1, 0, kt); SU_B(buf, 1, 1, kt);                                 \
    SU_A(buf, 0, 0, kt); SU_A(buf, 1, 0, kt);                                 \
    SU_A(buf, 0, 1, kt); SU_A(buf, 1, 1, kt);                                 \
} while (0)

    const int lq = l >> 4;
    const int lr = l & 15;

    f16x8 af0[4][2], af1[4][2], bf0[2][2], bf1[2][2];

#define READ_AF(D, h, ARR) do {                                               \
    _Pragma("unroll")                                                         \
    for (int mi = 0; mi < 4; ++mi) {                                          \
        const int lrow = (h) * 64 + mi * 16 + lr;                             \
        _Pragma("unroll")                                                     \
        for (int ks = 0; ks < 2; ++ks)                                        \
            ARR[mi][ks] = *(const f16x8*)                                     \
                &LA[D][wr][lrow * 64 + (((ks * 4 + lq) ^ (lrow & 7)) * 8)];   \
    }                                                                         \
} while (0)

#define READ_BF(D, ch, ARR) do {                                              \
    _Pragma("unroll")                                                         \
    for (int n = 0; n < 2; ++n) {                                             \
        const int lrow = (wc & 1) * 64 + (ch) * 32 + n * 16 + lr;             \
        _Pragma("unroll")                                                     \
        for (int ks = 0; ks < 2; ++ks)                                        \
            ARR[n][ks] = *(const f16x8*)                                      \
                &LB[D][wc >> 1][lrow * 64 + (((ks * 4 + lq) ^ (lrow & 7)) * 8)]; \
    }                                                                         \
} while (0)

    // 16 MFMA cluster: ks outer (dependency distance 8)
#define Q16(MB, AF, BF, NB) do {                                              \
    __builtin_amdgcn_s_setprio(1);                                            \
    _Pragma("unroll")                                                         \
    for (int ks = 0; ks < 2; ++ks)                                            \
        _Pragma("unroll")                                                     \
        for (int mi = 0; mi < 4; ++mi)                                        \
            _Pragma("unroll")                                                 \
            for (int n = 0; n < 2; ++n)                                       \
                acc[(MB) + mi][(NB) + n] =                                    \
                    __builtin_amdgcn_mfma_f32_16x16x32_f16(                   \
                        AF[mi][ks], BF[n][ks], acc[(MB) + mi][(NB) + n],      \
                        0, 0, 0);                                             \
    __builtin_amdgcn_s_setprio(0);                                            \
} while (0)

#define WAITV(n) asm volatile("s_waitcnt vmcnt(" #n ")" ::: "memory")
#define BAR()    __builtin_amdgcn_s_barrier()

    // tile k from dbuf D; stage tile ktn (=k+1) into DN right away.
    // Entry WAITV(0): drains D's 8 units, issued one full tile ago -> free.
    // Entry BAR: every wave's reads of DN (tile k-1) completed pre-BAR
    // (their values were consumed by MFMAs, compiler lgkm-waits) -> the
    // STAGE8 DMA into DN cannot race them.
#define TILE_STD(D, DN, ktn) do {                                             \
    WAITV(0); BAR();                                                          \
    STAGE8(DN, ktn);                                                          \
    READ_AF(D, 0, af0); READ_BF(D, 0, bf0);                                   \
    Q16(0, af0, bf0, 0);                                                      \
    READ_BF(D, 1, bf1);                                                       \
    Q16(0, af0, bf1, 2);                                                      \
    READ_AF(D, 1, af1);                                                       \
    Q16(4, af1, bf1, 2);                                                      \
    Q16(4, af1, bf0, 0);                                                      \
} while (0)

#define TILE_LAST(D) do {                                                     \
    WAITV(0); BAR();                                                          \
    READ_AF(D, 0, af0); READ_BF(D, 0, bf0);                                   \
    Q16(0, af0, bf0, 0);                                                      \
    READ_BF(D, 1, bf1);                                                       \
    Q16(0, af0, bf1, 2);                                                      \
    READ_AF(D, 1, af1);                                                       \
    Q16(4, af1, bf1, 2);                                                      \
    Q16(4, af1, bf0, 0);                                                      \
} while (0)

    // prologue: tile 0 -> dbuf0 (8 units outstanding)
    STAGE8(0, 0);

    for (int i = 0; i < 31; ++i) {
        TILE_STD(0, 1, 2 * i + 1);        // tile 2i,   stages 2i+1
        TILE_STD(1, 0, 2 * i + 2);        // tile 2i+1, stages 2i+2
    }
    TILE_STD(0, 1, 63);                   // tile 62, stages 63
    TILE_LAST(1);                         // tile 63

    // epilogue: per-column scale, f32 store
#pragma unroll
    for (int ni = 0; ni < 4; ++ni) {
        const int col = bn0 + wc * 64 + ni * 16 + lr;
        const float s = WS[col];
#pragma unroll
        for (int mi = 0; mi < 8; ++mi) {
            const int row = bm0 + wr * 128 + mi * 16 + lq * 4;
#pragma unroll
            for (int i = 0; i < 4; ++i) {
                Out[(size_t)(row + i) * N_DIM + col] = acc[mi][ni][i] * s;
            }
        }
    }
#undef SU_A
#undef SU_B
#undef STAGE8
#undef READ_AF
#undef READ_BF
#undef Q16
#undef WAITV
#undef BAR
#undef TILE_STD
#undef TILE_LAST
}

extern "C" void kernel_launch(void* const* d_in, const int* in_sizes, int n_in,
                              void* d_out, int out_size, void* d_ws, size_t ws_size,
                              hipStream_t stream) {
    const float* X  = (const float*)d_in[0];
    const int*   WP = (const int*)d_in[1];
    const float* WS = (const float*)d_in[2];
    float*       Out = (float*)d_out;

    unsigned short* Xh = (unsigned short*)d_ws;
    unsigned*       Wt = (unsigned*)((char*)d_ws + WS_XH_BYTES);

    cvt_x_kernel<<<(M_DIM * K_DIM) / (256 * 8), 256, 0, stream>>>(X, Xh);
    dim3 gdq(N_DIM / 64, KH / 64);                    // 172 x 32
    dqt_kernel<<<gdq, 256, 0, stream>>>(WP, Wt);
    dim3 grid((N_DIM / 256) * (M_DIM / 256));         // 688
    qgemm15_kernel<<<grid, 512, 0, stream>>>(Xh, Wt, WS, Out);
}

// Round 24
// 407.214 us; speedup vs baseline: 1.0744x; 1.0744x over previous
//
#include <hip/hip_runtime.h>
#include <hip/hip_fp16.h>
#include <stdint.h>

// SymmetricQuantLinear: out[m,n] = scale[n] * sum_k x[m,k] * (nib(k,n) - 8)
// FINAL (R22 keeper, reproduced at 406-408 us total, GEMM ~390 us = 947 TF,
//   MfmaUtil 41.6%, 0 bank conflicts, absmax 0.5).
// Structure: two-pass.
//   Pass 1a: X f32 -> fp16 (exact, values fp16-origin).
//   Pass 1b: WP int4-packed -> dequantized fp16 W^T [N][K] (exact ints,
//            scale factored out of the GEMM entirely).
//   Pass 2:  256x256 tile, BK=64, 8 waves, 2 LDS dbufs (128 KB);
//            counted-queue staging: 8x8KB gld_lds units per tile issued in
//            consumption order, WAITV(4)/WAITV(6) drain only >=2.5-phase-old
//            loads (never 0 mid-loop), 2 barriers/tile; 0-conflict XOR
//            swizzle (source-pre-swizzled, linear LDS dest); XCD pairing
//            (xcd owns M-row pairs -> B panels L2-shared); scale+store f32
//            epilogue. Alternatives all measured worse (R11-R23).

#define M_DIM 4096
#define K_DIM 4096
#define N_DIM 11008
#define KH    (K_DIM / 2)

#define WS_XH_BYTES  ((size_t)M_DIM * K_DIM * 2)            // 32 MiB

typedef __attribute__((ext_vector_type(8))) _Float16 f16x8;
typedef __attribute__((ext_vector_type(2))) _Float16 h2;
typedef __attribute__((ext_vector_type(4))) float f32x4;

__device__ __forceinline__ unsigned pack_f16_pair(float lo, float hi) {
    return __builtin_bit_cast(unsigned, __builtin_amdgcn_cvt_pkrtz(lo, hi));
}

__device__ __forceinline__ unsigned dq_pair(unsigned v) {
    unsigned c = (v & 0xFu) | ((v << 12) & 0x000F0000u) | 0x64006400u;
    h2 r = __builtin_bit_cast(h2, c) + __builtin_bit_cast(h2, 0xE408E408u);
    return __builtin_bit_cast(unsigned, r);
}

__device__ __forceinline__ void gld_lds16(const void* g, void* l) {
    __builtin_amdgcn_global_load_lds(
        (const __attribute__((address_space(1))) unsigned int*)g,
        (__attribute__((address_space(3))) unsigned int*)l,
        16, 0, 0);
}

// ---- Pass 1a: X f32 -> fp16 (exact) ----
__global__ void __launch_bounds__(256) cvt_x_kernel(
    const float* __restrict__ X, unsigned short* __restrict__ Xh)
{
    size_t i = ((size_t)blockIdx.x * 256 + threadIdx.x) * 8;
    float4 a = *(const float4*)(X + i);
    float4 b = *(const float4*)(X + i + 4);
    uint4 o = make_uint4(pack_f16_pair(a.x, a.y), pack_f16_pair(a.z, a.w),
                         pack_f16_pair(b.x, b.y), pack_f16_pair(b.z, b.w));
    *(uint4*)(Xh + i) = o;
}

// ---- Pass 1b: WP [KH][N] -> Wt uint32 [N][KH] ----
__global__ void __launch_bounds__(256) dqt_kernel(
    const int* __restrict__ WP, unsigned* __restrict__ Wt)
{
    __shared__ unsigned Lt[64][65];
    const int t = threadIdx.x;
    const int n0 = blockIdx.x * 64;
    const int r0 = blockIdx.y * 64;
    const int g = t >> 6, l = t & 63;
#pragma unroll
    for (int i = 0; i < 16; ++i) {
        const int r = r0 + g * 16 + i;
        Lt[l][g * 16 + i] = dq_pair((unsigned)WP[(size_t)r * N_DIM + n0 + l]);
    }
    __syncthreads();
    const int nr = t >> 2, sg = t & 3;
    unsigned* dst = Wt + (size_t)(n0 + nr) * KH + r0 + sg * 16;
#pragma unroll
    for (int c = 0; c < 4; ++c) {
        uint4 v = make_uint4(Lt[nr][sg * 16 + c * 4 + 0], Lt[nr][sg * 16 + c * 4 + 1],
                             Lt[nr][sg * 16 + c * 4 + 2], Lt[nr][sg * 16 + c * 4 + 3]);
        *(uint4*)(dst + c * 4) = v;
    }
}

// ---- Pass 2: counted-queue 8-phase fp16 GEMM (compiler-managed lgkm) ----
__global__ void __launch_bounds__(512, 2) qgemm14_kernel(
    const unsigned short* __restrict__ Xh,   // fp16 [M][K]
    const unsigned*       __restrict__ Wt,   // uint32 [N][KH] (fp16 [N][K])
    const float*          __restrict__ WS,   // [N]
    float*                __restrict__ Out)  // f32 [M][N]
{
    __shared__ unsigned short LA[2][2][8192];   // [dbuf][half][128 x 64]
    __shared__ unsigned short LB[2][2][8192];   // 128 KB total

    const int t = threadIdx.x;     // 0..511
    const int w = t >> 6;          // wave 0..7
    const int l = t & 63;

    // XCD pairing: xcd owns M-rows {2x,2x+1}, N-major (R14: FETCH 403 MB).
    const int bid = blockIdx.x;                 // 0..687
    const int xcd = bid & 7;
    const int i8  = bid >> 3;                   // 0..85
    const int bx  = i8 >> 1;                    // 0..42
    const int by  = (xcd << 1) | (i8 & 1);      // 0..15
    const int bm0 = by * 256;
    const int bn0 = bx * 256;

    const int wr = w >> 2;         // A half
    const int wc = w & 3;          // B: half = wc>>1, sub = wc&1

    f32x4 acc[8][4];
#pragma unroll
    for (int i = 0; i < 8; ++i)
#pragma unroll
        for (int j = 0; j < 4; ++j)
            acc[i][j] = (f32x4){0.f, 0.f, 0.f, 0.f};

    // staging: unit = 64 rows x 64 ushort = 8 KB = 512 threads x 16 B.
    const int cS = (t & 7) ^ ((t >> 3) & 7);
    const unsigned short* gA = Xh + (size_t)(bm0 + (t >> 3)) * K_DIM + cS * 8;
    const unsigned*       gB = Wt + (size_t)(bn0 + (t >> 3)) * KH + cS * 4;
    const int t8 = t * 8;

#define SU_A(buf, h, c, kt)                                                   \
    gld_lds16(gA + (size_t)((h) * 128 + (c) * 64) * K_DIM + (size_t)(kt) * 64, \
              &LA[buf][h][(c) * 4096 + t8])
#define SU_B(buf, bh, ch, kt)                                                 \
    gld_lds16(gB + (size_t)((bh) * 128 + (ch) * 64) * KH + (size_t)(kt) * 32, \
              &LB[buf][bh][(ch) * 4096 + t8])

    const int lq = l >> 4;
    const int lr = l & 15;

    f16x8 af0[4][2], af1[4][2], bf0[2][2], bf1[2][2];

#define READ_AF(D, h, ARR) do {                                               \
    _Pragma("unroll")                                                         \
    for (int mi = 0; mi < 4; ++mi) {                                          \
        const int lrow = (h) * 64 + mi * 16 + lr;                             \
        _Pragma("unroll")                                                     \
        for (int ks = 0; ks < 2; ++ks)                                        \
            ARR[mi][ks] = *(const f16x8*)                                     \
                &LA[D][wr][lrow * 64 + (((ks * 4 + lq) ^ (lrow & 7)) * 8)];   \
    }                                                                         \
} while (0)

#define READ_BF(D, ch, ARR) do {                                              \
    _Pragma("unroll")                                                         \
    for (int n = 0; n < 2; ++n) {                                             \
        const int lrow = (wc & 1) * 64 + (ch) * 32 + n * 16 + lr;             \
        _Pragma("unroll")                                                     \
        for (int ks = 0; ks < 2; ++ks)                                        \
            ARR[n][ks] = *(const f16x8*)                                      \
                &LB[D][wc >> 1][lrow * 64 + (((ks * 4 + lq) ^ (lrow & 7)) * 8)]; \
    }                                                                         \
} while (0)

    // 16 MFMA cluster: ks outer (dependency distance 8)
#define Q16(MB, AF, BF, NB) do {                                              \
    __builtin_amdgcn_s_setprio(1);                                            \
    _Pragma("unroll")                                                         \
    for (int ks = 0; ks < 2; ++ks)                                            \
        _Pragma("unroll")                                                     \
        for (int mi = 0; mi < 4; ++mi)                                        \
            _Pragma("unroll")                                                 \
            for (int n = 0; n < 2; ++n)                                       \
                acc[(MB) + mi][(NB) + n] =                                    \
                    __builtin_amdgcn_mfma_f32_16x16x32_f16(                   \
                        AF[mi][ks], BF[n][ks], acc[(MB) + mi][(NB) + n],      \
                        0, 0, 0);                                             \
    __builtin_amdgcn_s_setprio(0);                                            \
} while (0)

#define WAITV(n) asm volatile("s_waitcnt vmcnt(" #n ")" ::: "memory")
#define BAR()    __builtin_amdgcn_s_barrier()

    // process tile (dbuf D), stage tile ktn into DN. 2 barriers, 2 vmcnts.
#define TILE_STD(D, DN, ktn) do {                                             \
    SU_B(DN, 0, 0, ktn); SU_B(DN, 0, 1, ktn);                                 \
    WAITV(4); BAR();                                                          \
    READ_AF(D, 0, af0); READ_BF(D, 0, bf0);                                   \
    Q16(0, af0, bf0, 0);                                                      \
    SU_B(DN, 1, 0, ktn); SU_B(DN, 1, 1, ktn);                                 \
    READ_BF(D, 1, bf1);                                                       \
    Q16(0, af0, bf1, 2);                                                      \
    SU_A(DN, 0, 0, ktn); SU_A(DN, 1, 0, ktn);                                 \
    WAITV(6); BAR();                                                          \
    READ_AF(D, 1, af1);                                                       \
    Q16(4, af1, bf1, 2);                                                      \
    SU_A(DN, 0, 1, ktn); SU_A(DN, 1, 1, ktn);                                 \
    Q16(4, af1, bf0, 0);                                                      \
} while (0)

#define TILE_LAST(D) do {                                                     \
    WAITV(2); BAR();                                                          \
    READ_AF(D, 0, af0); READ_BF(D, 0, bf0);                                   \
    Q16(0, af0, bf0, 0);                                                      \
    READ_BF(D, 1, bf1);                                                       \
    Q16(0, af0, bf1, 2);                                                      \
    WAITV(0); BAR();                                                          \
    READ_AF(D, 1, af1);                                                       \
    Q16(4, af1, bf1, 2);                                                      \
    Q16(4, af1, bf0, 0);                                                      \
} while (0)

    // prologue: tile 0 units in consumption order
    SU_B(0, 0, 0, 0); SU_B(0, 0, 1, 0); SU_B(0, 1, 0, 0); SU_B(0, 1, 1, 0);
    SU_A(0, 0, 0, 0); SU_A(0, 1, 0, 0); SU_A(0, 0, 1, 0); SU_A(0, 1, 1, 0);

    for (int i = 0; i < 31; ++i) {
        TILE_STD(0, 1, 2 * i + 1);        // tile 2i,   stages 2i+1
        TILE_STD(1, 0, 2 * i + 2);        // tile 2i+1, stages 2i+2
    }
    TILE_STD(0, 1, 63);                   // tile 62, stages 63
    TILE_LAST(1);                         // tile 63

    // epilogue: per-column scale, f32 store
#pragma unroll
    for (int ni = 0; ni < 4; ++ni) {
        const int col = bn0 + wc * 64 + ni * 16 + lr;
        const float s = WS[col];
#pragma unroll
        for (int mi = 0; mi < 8; ++mi) {
            const int row = bm0 + wr * 128 + mi * 16 + lq * 4;
#pragma unroll
            for (int i = 0; i < 4; ++i) {
                Out[(size_t)(row + i) * N_DIM + col] = acc[mi][ni][i] * s;
            }
        }
    }
#undef SU_A
#undef SU_B
#undef READ_AF
#undef READ_BF
#undef Q16
#undef WAITV
#undef BAR
#undef TILE_STD
#undef TILE_LAST
}

extern "C" void kernel_launch(void* const* d_in, const int* in_sizes, int n_in,
                              void* d_out, int out_size, void* d_ws, size_t ws_size,
                              hipStream_t stream) {
    const float* X  = (const float*)d_in[0];
    const int*   WP = (const int*)d_in[1];
    const float* WS = (const float*)d_in[2];
    float*       Out = (float*)d_out;

    unsigned short* Xh = (unsigned short*)d_ws;
    unsigned*       Wt = (unsigned*)((char*)d_ws + WS_XH_BYTES);

    cvt_x_kernel<<<(M_DIM * K_DIM) / (256 * 8), 256, 0, stream>>>(X, Xh);
    dim3 gdq(N_DIM / 64, KH / 64);                    // 172 x 32
    dqt_kernel<<<gdq, 256, 0, stream>>>(WP, Wt);
    dim3 grid((N_DIM / 256) * (M_DIM / 256));         // 688
    qgemm14_kernel<<<grid, 512, 0, stream>>>(Xh, Wt, WS, Out);
}